// Round 1
// baseline (156.055 us; speedup 1.0000x reference)
//
#include <hip/hip_runtime.h>
#include <math.h>

#define BATCH 16
#define SEQ   4096
#define HDIM  1024
#define DV    2048          // 2*H
#define NCH   32            // s-chunks for context partials
#define SCH   (SEQ / NCH)   // 128

__device__ __forceinline__ float tanh_fast(float x) {
    // tanh(x) = 1 - 2/(1+exp(2x)); robust at +/-inf: exp->inf => 1, exp->0 => -1
    float e = __expf(2.0f * x);
    return 1.0f - 2.0f * __builtin_amdgcn_rcpf(1.0f + e);
}

// K1: q[b,o] = sum_h query[b,h] * Wq[o,h]   (wave per o, loop over b)
__global__ __launch_bounds__(256) void k1_q(const float* __restrict__ query,
                                            const float* __restrict__ Wq,
                                            float* __restrict__ qout) {
    int wave = threadIdx.x >> 6;
    int lane = threadIdx.x & 63;
    int o = blockIdx.x * 4 + wave;
    const float4* wq4 = (const float4*)(Wq + (size_t)o * HDIM);
    float4 w[4];
#pragma unroll
    for (int k = 0; k < 4; ++k) w[k] = wq4[k * 64 + lane];   // contiguous across lanes
#pragma unroll
    for (int b = 0; b < BATCH; ++b) {
        const float4* q4 = (const float4*)(query + b * HDIM);
        float acc = 0.f;
#pragma unroll
        for (int k = 0; k < 4; ++k) {
            float4 q = q4[k * 64 + lane];
            acc += w[k].x * q.x + w[k].y * q.y + w[k].z * q.z + w[k].w * q.w;
        }
#pragma unroll
        for (int off = 32; off; off >>= 1) acc += __shfl_down(acc, off, 64);
        if (lane == 0) qout[b * HDIM + o] = acc;
    }
}

// K2: scores[b,s] = sum_h tanh(q[b,h] + pk[b,s,h]) * we[h], masked -> -inf
//     one wave per (b,s) row
__global__ __launch_bounds__(256) void k2_scores(const float* __restrict__ pk,
                                                 const float* __restrict__ qv,
                                                 const float* __restrict__ we,
                                                 const int* __restrict__ mask,
                                                 float* __restrict__ scores) {
    int wave = threadIdx.x >> 6;
    int lane = threadIdx.x & 63;
    int r = blockIdx.x * 4 + wave;           // row in [0, B*S)
    int b = r >> 12;                         // S = 4096 = 2^12
    const float4* row = (const float4*)(pk + (size_t)r * HDIM);
    const float4* q4  = (const float4*)(qv + b * HDIM);
    const float4* we4 = (const float4*)we;
    float acc = 0.f;
#pragma unroll
    for (int k = 0; k < 4; ++k) {
        int idx = k * 64 + lane;             // contiguous float4 across lanes
        float4 p = row[idx];
        float4 q = q4[idx];
        float4 w = we4[idx];
        acc += tanh_fast(p.x + q.x) * w.x;
        acc += tanh_fast(p.y + q.y) * w.y;
        acc += tanh_fast(p.z + q.z) * w.z;
        acc += tanh_fast(p.w + q.w) * w.w;
    }
#pragma unroll
    for (int off = 32; off; off >>= 1) acc += __shfl_down(acc, off, 64);
    if (lane == 0) scores[r] = (mask[r] == 0) ? -INFINITY : acc;
}

// K3: softmax over S per batch row; writes alphas into d_out alphas region
__global__ __launch_bounds__(256) void k3_softmax(const float* __restrict__ scores,
                                                  float* __restrict__ alphas) {
    int b = blockIdx.x;
    int t = threadIdx.x;
    const float* sc = scores + b * SEQ;
    float loc[16];
    float m = -INFINITY;
#pragma unroll
    for (int i = 0; i < 16; ++i) {
        loc[i] = sc[t + i * 256];
        m = fmaxf(m, loc[i]);
    }
#pragma unroll
    for (int off = 32; off; off >>= 1) m = fmaxf(m, __shfl_down(m, off, 64));
    __shared__ float redm[4];
    if ((t & 63) == 0) redm[t >> 6] = m;
    __syncthreads();
    m = fmaxf(fmaxf(redm[0], redm[1]), fmaxf(redm[2], redm[3]));

    float sum = 0.f;
#pragma unroll
    for (int i = 0; i < 16; ++i) {
        loc[i] = __expf(loc[i] - m);         // exp(-inf - m) = 0 for masked
        sum += loc[i];
    }
#pragma unroll
    for (int off = 32; off; off >>= 1) sum += __shfl_down(sum, off, 64);
    __shared__ float reds[4];
    if ((t & 63) == 0) reds[t >> 6] = sum;
    __syncthreads();
    float inv = 1.0f / (reds[0] + reds[1] + reds[2] + reds[3]);
#pragma unroll
    for (int i = 0; i < 16; ++i)
        alphas[b * SEQ + t + i * 256] = loc[i] * inv;
}

// K4: context partials. bid = b*64 + dt*32 + ch. Each block: 1024 d-cols over 128 s.
__global__ __launch_bounds__(256) void k4_part(const float* __restrict__ value,
                                               const float* __restrict__ alphas,
                                               float* __restrict__ part) {
    int bid = blockIdx.x;
    int ch = bid & (NCH - 1);
    int dt = (bid >> 5) & 1;
    int b  = bid >> 6;
    int t  = threadIdx.x;
    const float4* v4 = (const float4*)(value + (size_t)b * SEQ * DV + dt * 1024);
    const float* al = alphas + b * SEQ + ch * SCH;
    float4 acc = make_float4(0.f, 0.f, 0.f, 0.f);
    for (int s = 0; s < SCH; ++s) {
        float a = al[s];
        float4 v = v4[(size_t)(ch * SCH + s) * (DV / 4) + t];
        acc.x += a * v.x; acc.y += a * v.y; acc.z += a * v.z; acc.w += a * v.w;
    }
    ((float4*)(part + (size_t)bid * 1024))[t] = acc;
}

// K4b: atomic fallback if workspace is too small for partials
__global__ __launch_bounds__(256) void k4_atomic(const float* __restrict__ value,
                                                 const float* __restrict__ alphas,
                                                 float* __restrict__ ctx) {
    int bid = blockIdx.x;
    int ch = bid & (NCH - 1);
    int dt = (bid >> 5) & 1;
    int b  = bid >> 6;
    int t  = threadIdx.x;
    const float4* v4 = (const float4*)(value + (size_t)b * SEQ * DV + dt * 1024);
    const float* al = alphas + b * SEQ + ch * SCH;
    float4 acc = make_float4(0.f, 0.f, 0.f, 0.f);
    for (int s = 0; s < SCH; ++s) {
        float a = al[s];
        float4 v = v4[(size_t)(ch * SCH + s) * (DV / 4) + t];
        acc.x += a * v.x; acc.y += a * v.y; acc.z += a * v.z; acc.w += a * v.w;
    }
    float* dst = ctx + (size_t)b * DV + dt * 1024 + t * 4;
    atomicAdd(dst + 0, acc.x);
    atomicAdd(dst + 1, acc.y);
    atomicAdd(dst + 2, acc.z);
    atomicAdd(dst + 3, acc.w);
}

// K5: reduce NCH partials -> context in d_out
__global__ __launch_bounds__(256) void k5_reduce(const float* __restrict__ part,
                                                 float* __restrict__ ctx) {
    int o = blockIdx.x * 256 + threadIdx.x;  // 0 .. B*DV-1
    int i = o & 1023;
    int g = o >> 10;                         // b*2 + dt
    const float* p = part + (size_t)g * (NCH * 1024) + i;
    float sum = 0.f;
#pragma unroll
    for (int c = 0; c < NCH; ++c) sum += p[c * 1024];
    ctx[o] = sum;
}

extern "C" void kernel_launch(void* const* d_in, const int* in_sizes, int n_in,
                              void* d_out, int out_size, void* d_ws, size_t ws_size,
                              hipStream_t stream) {
    const float* query = (const float*)d_in[0];
    const float* pk    = (const float*)d_in[1];
    const float* value = (const float*)d_in[2];
    const float* Wq    = (const float*)d_in[3];
    const float* we    = (const float*)d_in[4];
    const int*   mask  = (const int*)d_in[5];

    float* out    = (float*)d_out;
    float* ctx    = out;                      // [B, 2H] = 32768 floats
    float* alphas = out + BATCH * DV;         // [B, S]  = 65536 floats

    float* ws     = (float*)d_ws;
    float* qws    = ws;                       // 16384 floats
    float* scores = ws + BATCH * HDIM;        // 65536 floats
    float* part   = scores + BATCH * SEQ;     // 1024*1024 floats

    k1_q<<<HDIM / 4, 256, 0, stream>>>(query, Wq, qws);
    k2_scores<<<(BATCH * SEQ) / 4, 256, 0, stream>>>(pk, qws, we, mask, scores);
    k3_softmax<<<BATCH, 256, 0, stream>>>(scores, alphas);

    size_t need = (size_t)(BATCH * HDIM + BATCH * SEQ + BATCH * 2 * NCH * 1024) * sizeof(float);
    if (ws_size >= need) {
        k4_part<<<BATCH * 2 * NCH, 256, 0, stream>>>(value, alphas, part);
        k5_reduce<<<(BATCH * DV) / 256, 256, 0, stream>>>(part, ctx);
    } else {
        hipMemsetAsync(ctx, 0, (size_t)BATCH * DV * sizeof(float), stream);
        k4_atomic<<<BATCH * 2 * NCH, 256, 0, stream>>>(value, alphas, ctx);
    }
}

// Round 2
// 117.378 us; speedup vs baseline: 1.3295x; 1.3295x over previous
//
#include <hip/hip_runtime.h>
#include <math.h>

#define BATCH 16
#define SEQ   4096
#define HDIM  1024
#define DV    2048          // 2*H
#define NCH2  64            // s-chunks in fused kernel
#define SCH2  (SEQ / NCH2)  // 64 rows per chunk

__device__ __forceinline__ float tanh_fast(float x) {
    // tanh(x) = 1 - 2/(1+exp(2x)); robust at +/-inf
    float e = __expf(2.0f * x);
    return 1.0f - 2.0f * __builtin_amdgcn_rcpf(1.0f + e);
}

__device__ __forceinline__ float max4(float4 v) {
    return fmaxf(fmaxf(v.x, v.y), fmaxf(v.z, v.w));
}

// K1: q[b,o] = sum_h query[b,h] * Wq[o,h]   (wave per o, loop over b)
__global__ __launch_bounds__(256) void k1_q(const float* __restrict__ query,
                                            const float* __restrict__ Wq,
                                            float* __restrict__ qout) {
    int wave = threadIdx.x >> 6;
    int lane = threadIdx.x & 63;
    int o = blockIdx.x * 4 + wave;
    const float4* wq4 = (const float4*)(Wq + (size_t)o * HDIM);
    float4 w[4];
#pragma unroll
    for (int k = 0; k < 4; ++k) w[k] = wq4[k * 64 + lane];
#pragma unroll
    for (int b = 0; b < BATCH; ++b) {
        const float4* q4 = (const float4*)(query + b * HDIM);
        float acc = 0.f;
#pragma unroll
        for (int k = 0; k < 4; ++k) {
            float4 q = q4[k * 64 + lane];
            acc += w[k].x * q.x + w[k].y * q.y + w[k].z * q.z + w[k].w * q.w;
        }
#pragma unroll
        for (int off = 32; off; off >>= 1) acc += __shfl_down(acc, off, 64);
        if (lane == 0) qout[b * HDIM + o] = acc;
    }
}

// KF: fused scores + chunk-local exp + context partials.
// Grid: B*NCH2 blocks (bid = b*64 + c), 256 threads (4 waves).
// Phase 1: wave w computes rows s0+w*16..+15 (SKIP pk read if masked).
// Phase 2: chunk max m_c, a_s = exp(sc - m_c); partial[bid][:] = sum a_s * value_row
//          (SKIP value row read if a_s == 0).
__global__ __launch_bounds__(256) void kf_fused(const float* __restrict__ pk,
                                                const float* __restrict__ qv,
                                                const float* __restrict__ we,
                                                const int* __restrict__ mask,
                                                const float* __restrict__ value,
                                                float* __restrict__ scores,
                                                float* __restrict__ partial) {
    int bid = blockIdx.x;
    int b = bid >> 6;
    int c = bid & (NCH2 - 1);
    int s0 = c * SCH2;
    int t = threadIdx.x;
    int wave = t >> 6;
    int lane = t & 63;

    __shared__ float s_sc[SCH2];
    __shared__ float s_a[SCH2];

    const float4* q4  = (const float4*)(qv + b * HDIM);
    const float4* we4 = (const float4*)we;
    float4 qr[4], wr[4];
#pragma unroll
    for (int k = 0; k < 4; ++k) {
        qr[k] = q4[k * 64 + lane];
        wr[k] = we4[k * 64 + lane];
    }

    // ---- phase 1: scores for 16 rows per wave ----
    for (int i = 0; i < 16; ++i) {
        int s = s0 + wave * 16 + i;
        int r = b * SEQ + s;
        float sc;
        if (mask[r] == 0) {
            sc = -INFINITY;                 // skip the 4KB pk row read
        } else {
            const float4* row = (const float4*)(pk + (size_t)r * HDIM);
            float acc = 0.f;
#pragma unroll
            for (int k = 0; k < 4; ++k) {
                float4 p = row[k * 64 + lane];
                acc += tanh_fast(p.x + qr[k].x) * wr[k].x;
                acc += tanh_fast(p.y + qr[k].y) * wr[k].y;
                acc += tanh_fast(p.z + qr[k].z) * wr[k].z;
                acc += tanh_fast(p.w + qr[k].w) * wr[k].w;
            }
#pragma unroll
            for (int off = 32; off; off >>= 1) acc += __shfl_down(acc, off, 64);
            sc = acc;
        }
        if (lane == 0) {
            s_sc[wave * 16 + i] = sc;
            scores[r] = sc;
        }
    }
    __syncthreads();

    // ---- chunk max + weights ----
    float mc = -INFINITY;
#pragma unroll 8
    for (int s = 0; s < SCH2; ++s) mc = fmaxf(mc, s_sc[s]);   // LDS broadcast reads
    if (t < SCH2)
        s_a[t] = (mc == -INFINITY) ? 0.f : __expf(s_sc[t] - mc);
    __syncthreads();

    // ---- phase 2: weighted value accumulation ----
    const float4* v4 = (const float4*)(value + (size_t)b * SEQ * DV);
    float4 a0 = make_float4(0.f, 0.f, 0.f, 0.f);
    float4 a1 = make_float4(0.f, 0.f, 0.f, 0.f);
    for (int s = 0; s < SCH2; ++s) {
        float a = s_a[s];
        if (a != 0.f) {                     // block-uniform skip of 8KB value row
            const float4* vr = v4 + (size_t)(s0 + s) * (DV / 4);
            float4 u = vr[t];
            float4 v = vr[t + 256];
            a0.x += a * u.x; a0.y += a * u.y; a0.z += a * u.z; a0.w += a * u.w;
            a1.x += a * v.x; a1.y += a * v.y; a1.z += a * v.z; a1.w += a * v.w;
        }
    }
    float4* pout = (float4*)(partial + (size_t)bid * DV);
    pout[t] = a0;
    pout[t + 256] = a1;
}

// KZ: finalize. Grid 64 blocks (bid = b*4 + q), 256 threads.
// Recomputes global m, Z and per-chunk m_c from scores; writes alphas quarter q
// and ctx columns [q*512, q*512+512).
__global__ __launch_bounds__(256) void kz_final(const float* __restrict__ scores,
                                                const float* __restrict__ partial,
                                                float* __restrict__ ctx,
                                                float* __restrict__ alphas) {
    int bid = blockIdx.x;
    int b = bid >> 2;
    int q = bid & 3;
    int t = threadIdx.x;
    int wave = t >> 6;
    int lane = t & 63;

    __shared__ float lmax[1024];
    __shared__ float gs[NCH2];
    __shared__ float redm[4];
    __shared__ float reds[4];

    const float4* sc4 = (const float4*)(scores + (size_t)b * SEQ);
    float4 v[4];
    float m = -INFINITY;
#pragma unroll
    for (int i = 0; i < 4; ++i) {
        v[i] = sc4[t + i * 256];
        m = fmaxf(m, max4(v[i]));
        lmax[t + i * 256] = max4(v[i]);
    }
#pragma unroll
    for (int off = 32; off; off >>= 1) m = fmaxf(m, __shfl_down(m, off, 64));
    if (lane == 0) redm[wave] = m;
    __syncthreads();
    m = fmaxf(fmaxf(redm[0], redm[1]), fmaxf(redm[2], redm[3]));

    float4 e[4];
    float sum = 0.f;
#pragma unroll
    for (int i = 0; i < 4; ++i) {
        e[i].x = __expf(v[i].x - m);
        e[i].y = __expf(v[i].y - m);
        e[i].z = __expf(v[i].z - m);
        e[i].w = __expf(v[i].w - m);
        sum += e[i].x + e[i].y + e[i].z + e[i].w;
    }
#pragma unroll
    for (int off = 32; off; off >>= 1) sum += __shfl_down(sum, off, 64);
    if (lane == 0) reds[wave] = sum;
    __syncthreads();
    float Z = reds[0] + reds[1] + reds[2] + reds[3];
    float inv = 1.0f / Z;

    // alphas quarter q: float4 index q*256 + t holds e[q]*inv
    float4 aout = make_float4(e[q].x * inv, e[q].y * inv, e[q].z * inv, e[q].w * inv);
    ((float4*)(alphas + (size_t)b * SEQ))[q * 256 + t] = aout;

    // per-chunk scale factors g_c = exp(m_c - m)
    __syncthreads();   // lmax fully written
    if (t < NCH2) {
        float mcv = -INFINITY;
#pragma unroll
        for (int j = 0; j < 16; ++j) mcv = fmaxf(mcv, lmax[t * 16 + j]);
        gs[t] = (mcv == -INFINITY) ? 0.f : __expf(mcv - m);
    }
    __syncthreads();

    // ctx columns: float2 at col q*512 + 2t, summed over 64 chunks
    float sx = 0.f, sy = 0.f;
    for (int cc = 0; cc < NCH2; ++cc) {
        float g = gs[cc];
        if (g != 0.f) {
            const float2* p2 = (const float2*)(partial + (size_t)(b * NCH2 + cc) * DV);
            float2 pv = p2[q * 256 + t];
            sx += g * pv.x;
            sy += g * pv.y;
        }
    }
    ((float2*)(ctx + (size_t)b * DV))[q * 256 + t] = make_float2(sx * inv, sy * inv);
}

// ---------- fallback path (tiny ws) ----------
__global__ __launch_bounds__(256) void k2_scores(const float* __restrict__ pk,
                                                 const float* __restrict__ qv,
                                                 const float* __restrict__ we,
                                                 const int* __restrict__ mask,
                                                 float* __restrict__ scores) {
    int wave = threadIdx.x >> 6;
    int lane = threadIdx.x & 63;
    int r = blockIdx.x * 4 + wave;
    int b = r >> 12;
    if (mask[r] == 0) { if (lane == 0) scores[r] = -INFINITY; return; }
    const float4* row = (const float4*)(pk + (size_t)r * HDIM);
    const float4* q4  = (const float4*)(qv + b * HDIM);
    const float4* we4 = (const float4*)we;
    float acc = 0.f;
#pragma unroll
    for (int k = 0; k < 4; ++k) {
        int idx = k * 64 + lane;
        float4 p = row[idx];
        float4 q = q4[idx];
        float4 w = we4[idx];
        acc += tanh_fast(p.x + q.x) * w.x;
        acc += tanh_fast(p.y + q.y) * w.y;
        acc += tanh_fast(p.z + q.z) * w.z;
        acc += tanh_fast(p.w + q.w) * w.w;
    }
#pragma unroll
    for (int off = 32; off; off >>= 1) acc += __shfl_down(acc, off, 64);
    if (lane == 0) scores[r] = acc;
}

__global__ __launch_bounds__(256) void k3_softmax(const float* __restrict__ scores,
                                                  float* __restrict__ alphas) {
    int b = blockIdx.x;
    int t = threadIdx.x;
    const float* sc = scores + b * SEQ;
    float loc[16];
    float m = -INFINITY;
#pragma unroll
    for (int i = 0; i < 16; ++i) { loc[i] = sc[t + i * 256]; m = fmaxf(m, loc[i]); }
#pragma unroll
    for (int off = 32; off; off >>= 1) m = fmaxf(m, __shfl_down(m, off, 64));
    __shared__ float redm[4];
    if ((t & 63) == 0) redm[t >> 6] = m;
    __syncthreads();
    m = fmaxf(fmaxf(redm[0], redm[1]), fmaxf(redm[2], redm[3]));
    float sum = 0.f;
#pragma unroll
    for (int i = 0; i < 16; ++i) { loc[i] = __expf(loc[i] - m); sum += loc[i]; }
#pragma unroll
    for (int off = 32; off; off >>= 1) sum += __shfl_down(sum, off, 64);
    __shared__ float reds[4];
    if ((t & 63) == 0) reds[t >> 6] = sum;
    __syncthreads();
    float inv = 1.0f / (reds[0] + reds[1] + reds[2] + reds[3]);
#pragma unroll
    for (int i = 0; i < 16; ++i) alphas[b * SEQ + t + i * 256] = loc[i] * inv;
}

__global__ __launch_bounds__(256) void k4_atomic(const float* __restrict__ value,
                                                 const float* __restrict__ alphas,
                                                 float* __restrict__ ctx) {
    int bid = blockIdx.x;
    int ch = bid & 31;
    int dt = (bid >> 5) & 1;
    int b  = bid >> 6;
    int t  = threadIdx.x;
    const float4* v4 = (const float4*)(value + (size_t)b * SEQ * DV + dt * 1024);
    const float* al = alphas + b * SEQ + ch * 128;
    float4 acc = make_float4(0.f, 0.f, 0.f, 0.f);
    for (int s = 0; s < 128; ++s) {
        float a = al[s];
        if (a != 0.f) {
            float4 v = v4[(size_t)(ch * 128 + s) * (DV / 4) + t];
            acc.x += a * v.x; acc.y += a * v.y; acc.z += a * v.z; acc.w += a * v.w;
        }
    }
    float* dst = ctx + (size_t)b * DV + dt * 1024 + t * 4;
    atomicAdd(dst + 0, acc.x);
    atomicAdd(dst + 1, acc.y);
    atomicAdd(dst + 2, acc.z);
    atomicAdd(dst + 3, acc.w);
}

extern "C" void kernel_launch(void* const* d_in, const int* in_sizes, int n_in,
                              void* d_out, int out_size, void* d_ws, size_t ws_size,
                              hipStream_t stream) {
    const float* query = (const float*)d_in[0];
    const float* pk    = (const float*)d_in[1];
    const float* value = (const float*)d_in[2];
    const float* Wq    = (const float*)d_in[3];
    const float* we    = (const float*)d_in[4];
    const int*   mask  = (const int*)d_in[5];

    float* out    = (float*)d_out;
    float* ctx    = out;                      // [B, 2H]
    float* alphas = out + BATCH * DV;         // [B, S]

    float* ws     = (float*)d_ws;
    float* qws    = ws;                                  // 16384 floats
    float* scores = ws + BATCH * HDIM;                   // 65536 floats
    float* partial = scores + BATCH * SEQ;               // B*NCH2*DV = 2M floats

    k1_q<<<HDIM / 4, 256, 0, stream>>>(query, Wq, qws);

    size_t need = (size_t)(BATCH * HDIM + BATCH * SEQ + BATCH * NCH2 * DV) * sizeof(float);
    if (ws_size >= need) {
        kf_fused<<<BATCH * NCH2, 256, 0, stream>>>(pk, qws, we, mask, value, scores, partial);
        kz_final<<<BATCH * 4, 256, 0, stream>>>(scores, partial, ctx, alphas);
    } else {
        k2_scores<<<(BATCH * SEQ) / 4, 256, 0, stream>>>(pk, qws, we, mask, scores);
        k3_softmax<<<BATCH, 256, 0, stream>>>(scores, alphas);
        hipMemsetAsync(ctx, 0, (size_t)BATCH * DV * sizeof(float), stream);
        k4_atomic<<<BATCH * 64, 256, 0, stream>>>(value, alphas, ctx);
    }
}

// Round 4
// 95.285 us; speedup vs baseline: 1.6378x; 1.2319x over previous
//
#include <hip/hip_runtime.h>
#include <math.h>

#define BATCH 16
#define SEQ   4096
#define HDIM  1024
#define DV    2048          // 2*H
#define NCH2  64            // s-chunks in fused kernel
#define SCH2  (SEQ / NCH2)  // 64 rows per chunk

typedef float vf4 __attribute__((ext_vector_type(4)));

__device__ __forceinline__ float tanh_fast(float x) {
    // tanh(x) = 1 - 2/(1+exp(2x)); robust at +/-inf
    float e = __expf(2.0f * x);
    return 1.0f - 2.0f * __builtin_amdgcn_rcpf(1.0f + e);
}

__device__ __forceinline__ float4 ntload4(const float4* p) {
    vf4 v = __builtin_nontemporal_load((const vf4*)p);
    return make_float4(v.x, v.y, v.z, v.w);
}

// K1: q[b,o] = sum_h query[b,h] * Wq[o,h]   (wave per o, loop over b)
__global__ __launch_bounds__(256) void k1_q(const float* __restrict__ query,
                                            const float* __restrict__ Wq,
                                            float* __restrict__ qout) {
    int wave = threadIdx.x >> 6;
    int lane = threadIdx.x & 63;
    int o = blockIdx.x * 4 + wave;
    const float4* wq4 = (const float4*)(Wq + (size_t)o * HDIM);
    float4 w[4];
#pragma unroll
    for (int k = 0; k < 4; ++k) w[k] = wq4[k * 64 + lane];
#pragma unroll
    for (int b = 0; b < BATCH; ++b) {
        const float4* q4 = (const float4*)(query + b * HDIM);
        float acc = 0.f;
#pragma unroll
        for (int k = 0; k < 4; ++k) {
            float4 q = q4[k * 64 + lane];
            acc += w[k].x * q.x + w[k].y * q.y + w[k].z * q.z + w[k].w * q.w;
        }
#pragma unroll
        for (int off = 32; off; off >>= 1) acc += __shfl_down(acc, off, 64);
        if (lane == 0) qout[b * HDIM + o] = acc;
    }
}

// KF: fused scores + chunk-local exp + context partials, with mask compaction.
// Grid: B*NCH2 blocks (bid = b*64 + c), 256 threads (4 waves).
__global__ __launch_bounds__(256) void kf_fused(const float* __restrict__ pk,
                                                const float* __restrict__ qv,
                                                const float* __restrict__ we,
                                                const int* __restrict__ mask,
                                                const float* __restrict__ value,
                                                float* __restrict__ scores,
                                                float* __restrict__ partial) {
    int bid = blockIdx.x;
    int b = bid >> 6;
    int c = bid & (NCH2 - 1);
    int s0 = c * SCH2;
    int t = threadIdx.x;
    int wave = t >> 6;
    int lane = t & 63;

    __shared__ float s_sc[SCH2];
    __shared__ float s_a[SCH2];
    __shared__ int   s_list[SCH2];
    __shared__ int   s_nact;

    // ---- compaction: wave 0 reads the chunk's 64 masks in one coalesced load ----
    if (t < SCH2) {
        int r = b * SEQ + s0 + t;
        int pred = (mask[r] != 0);
        unsigned long long bal = __ballot(pred);
        if (pred) {
            int pos = __popcll(bal & ((1ull << lane) - 1ull));
            s_list[pos] = t;
        } else {
            s_sc[t] = -INFINITY;
            scores[r] = -INFINITY;
        }
        if (lane == 0) s_nact = __popcll(bal);
    }

    const float4* q4  = (const float4*)(qv + b * HDIM);
    const float4* we4 = (const float4*)we;
    float4 qr[4], wr[4];
#pragma unroll
    for (int k = 0; k < 4; ++k) {
        qr[k] = q4[k * 64 + lane];
        wr[k] = we4[k * 64 + lane];
    }
    __syncthreads();
    int nact = s_nact;

    // ---- phase 1: scores for active rows only (wave-strided, balanced) ----
    for (int j = wave; j < nact; j += 4) {
        int s = s_list[j];
        int r = b * SEQ + s0 + s;
        const float4* row = (const float4*)(pk + (size_t)r * HDIM);
        float acc = 0.f;
#pragma unroll
        for (int k = 0; k < 4; ++k) {
            float4 p = ntload4(row + k * 64 + lane);
            acc += tanh_fast(p.x + qr[k].x) * wr[k].x;
            acc += tanh_fast(p.y + qr[k].y) * wr[k].y;
            acc += tanh_fast(p.z + qr[k].z) * wr[k].z;
            acc += tanh_fast(p.w + qr[k].w) * wr[k].w;
        }
#pragma unroll
        for (int off = 32; off; off >>= 1) acc += __shfl_down(acc, off, 64);
        if (lane == 0) {
            s_sc[s] = acc;
            scores[r] = acc;
        }
    }
    __syncthreads();

    // ---- chunk max + weights ----
    float mc = -INFINITY;
#pragma unroll 8
    for (int s = 0; s < SCH2; ++s) mc = fmaxf(mc, s_sc[s]);   // LDS broadcast
    if (t < SCH2)
        s_a[t] = (s_sc[t] == -INFINITY || mc == -INFINITY) ? 0.f : __expf(s_sc[t] - mc);
    __syncthreads();

    // ---- phase 2: weighted value accumulation over active rows ----
    const float4* v4 = (const float4*)(value + (size_t)b * SEQ * DV);
    float4 a0 = make_float4(0.f, 0.f, 0.f, 0.f);
    float4 a1 = make_float4(0.f, 0.f, 0.f, 0.f);
    for (int j = 0; j < nact; ++j) {
        int s = s_list[j];
        float a = s_a[s];
        const float4* vr = v4 + (size_t)(s0 + s) * (DV / 4);
        float4 u = ntload4(vr + t);
        float4 v = ntload4(vr + t + 256);
        a0.x += a * u.x; a0.y += a * u.y; a0.z += a * u.z; a0.w += a * u.w;
        a1.x += a * v.x; a1.y += a * v.y; a1.z += a * v.z; a1.w += a * v.w;
    }
    float4* pout = (float4*)(partial + (size_t)bid * DV);
    pout[t] = a0;
    pout[t + 256] = a1;
}

// KZ: finalize. Grid B*16 = 256 blocks (bid = b*16 + q), 256 threads.
// Each block: recompute m/Z from scores (L2-hot 16KB), write alphas rows
// [q*256, q*256+256) and ctx cols [q*128, q*128+128).
__global__ __launch_bounds__(256) void kz_final(const float* __restrict__ scores,
                                                const float* __restrict__ partial,
                                                float* __restrict__ ctx,
                                                float* __restrict__ alphas) {
    int bid = blockIdx.x;
    int b = bid >> 4;
    int q = bid & 15;
    int t = threadIdx.x;
    int wave = t >> 6;
    int lane = t & 63;

    __shared__ float s_raw[SEQ];
    __shared__ float s_g[NCH2];
    __shared__ float red[8];
    __shared__ float s_half[128];

    // load scores[b] into LDS (coalesced float4)
    const float4* sc4 = (const float4*)(scores + (size_t)b * SEQ);
    float4* raw4 = (float4*)s_raw;
#pragma unroll
    for (int i = 0; i < 4; ++i) raw4[t + i * 256] = sc4[t + i * 256];
    __syncthreads();

    // global max m (strided per-thread, conflict-free across lanes)
    float m = -INFINITY;
#pragma unroll
    for (int i = 0; i < 16; ++i) m = fmaxf(m, s_raw[t + i * 256]);
#pragma unroll
    for (int off = 32; off; off >>= 1) m = fmaxf(m, __shfl_down(m, off, 64));
    if (lane == 0) red[wave] = m;
    __syncthreads();
    m = fmaxf(fmaxf(red[0], red[1]), fmaxf(red[2], red[3]));

    // Z
    float z = 0.f;
#pragma unroll
    for (int i = 0; i < 16; ++i) {
        float v = s_raw[t + i * 256];
        z += (v == -INFINITY) ? 0.f : __expf(v - m);
    }
#pragma unroll
    for (int off = 32; off; off >>= 1) z += __shfl_down(z, off, 64);
    if (lane == 0) red[4 + wave] = z;
    __syncthreads();
    float Z = red[4] + red[5] + red[6] + red[7];
    float inv = 1.0f / Z;

    // per-chunk scale factors (rotated scan start -> no bank conflicts)
    if (t < NCH2) {
        float mcv = -INFINITY;
#pragma unroll 8
        for (int j = 0; j < SCH2; ++j)
            mcv = fmaxf(mcv, s_raw[t * SCH2 + ((j + t) & (SCH2 - 1))]);
        s_g[t] = (mcv == -INFINITY) ? 0.f : __expf(mcv - m);
    }

    // alphas rows [q*256, q*256+256)
    {
        float v = s_raw[q * 256 + t];
        float e = (v == -INFINITY) ? 0.f : __expf(v - m);
        alphas[(size_t)b * SEQ + q * 256 + t] = e * inv;
    }
    __syncthreads();

    // ctx cols [q*128, q*128+128): half 0 sums chunks 0..31, half 1 sums 32..63
    int col = q * 128 + (t & 127);
    int half = t >> 7;
    float sum = 0.f;
    const float* pbase = partial + (size_t)b * NCH2 * DV + col;
#pragma unroll 4
    for (int cc = half * 32; cc < half * 32 + 32; ++cc) {
        float g = s_g[cc];
        if (g != 0.f) sum += g * pbase[(size_t)cc * DV];
    }
    if (half == 1) s_half[t & 127] = sum;
    __syncthreads();
    if (half == 0)
        ctx[(size_t)b * DV + col] = (sum + s_half[t]) * inv;
}

// ---------- fallback path (tiny ws) ----------
__global__ __launch_bounds__(256) void k2_scores(const float* __restrict__ pk,
                                                 const float* __restrict__ qv,
                                                 const float* __restrict__ we,
                                                 const int* __restrict__ mask,
                                                 float* __restrict__ scores) {
    int wave = threadIdx.x >> 6;
    int lane = threadIdx.x & 63;
    int r = blockIdx.x * 4 + wave;
    int b = r >> 12;
    if (mask[r] == 0) { if (lane == 0) scores[r] = -INFINITY; return; }
    const float4* row = (const float4*)(pk + (size_t)r * HDIM);
    const float4* q4  = (const float4*)(qv + b * HDIM);
    const float4* we4 = (const float4*)we;
    float acc = 0.f;
#pragma unroll
    for (int k = 0; k < 4; ++k) {
        int idx = k * 64 + lane;
        float4 p = row[idx];
        float4 q = q4[idx];
        float4 w = we4[idx];
        acc += tanh_fast(p.x + q.x) * w.x;
        acc += tanh_fast(p.y + q.y) * w.y;
        acc += tanh_fast(p.z + q.z) * w.z;
        acc += tanh_fast(p.w + q.w) * w.w;
    }
#pragma unroll
    for (int off = 32; off; off >>= 1) acc += __shfl_down(acc, off, 64);
    if (lane == 0) scores[r] = acc;
}

__global__ __launch_bounds__(256) void k3_softmax(const float* __restrict__ scores,
                                                  float* __restrict__ alphas) {
    int b = blockIdx.x;
    int t = threadIdx.x;
    const float* sc = scores + b * SEQ;
    float loc[16];
    float m = -INFINITY;
#pragma unroll
    for (int i = 0; i < 16; ++i) { loc[i] = sc[t + i * 256]; m = fmaxf(m, loc[i]); }
#pragma unroll
    for (int off = 32; off; off >>= 1) m = fmaxf(m, __shfl_down(m, off, 64));
    __shared__ float redm[4];
    if ((t & 63) == 0) redm[t >> 6] = m;
    __syncthreads();
    m = fmaxf(fmaxf(redm[0], redm[1]), fmaxf(redm[2], redm[3]));
    float sum = 0.f;
#pragma unroll
    for (int i = 0; i < 16; ++i) {
        loc[i] = (loc[i] == -INFINITY) ? 0.f : __expf(loc[i] - m);
        sum += loc[i];
    }
#pragma unroll
    for (int off = 32; off; off >>= 1) sum += __shfl_down(sum, off, 64);
    __shared__ float reds[4];
    if ((t & 63) == 0) reds[t >> 6] = sum;
    __syncthreads();
    float inv = 1.0f / (reds[0] + reds[1] + reds[2] + reds[3]);
#pragma unroll
    for (int i = 0; i < 16; ++i) alphas[b * SEQ + t + i * 256] = loc[i] * inv;
}

__global__ __launch_bounds__(256) void k4_atomic(const float* __restrict__ value,
                                                 const float* __restrict__ alphas,
                                                 float* __restrict__ ctx) {
    int bid = blockIdx.x;
    int ch = bid & 31;
    int dt = (bid >> 5) & 1;
    int b  = bid >> 6;
    int t  = threadIdx.x;
    const float4* v4 = (const float4*)(value + (size_t)b * SEQ * DV + dt * 1024);
    const float* al = alphas + b * SEQ + ch * 128;
    float4 acc = make_float4(0.f, 0.f, 0.f, 0.f);
    for (int s = 0; s < 128; ++s) {
        float a = al[s];
        if (a != 0.f) {
            float4 v = v4[(size_t)(ch * 128 + s) * (DV / 4) + t];
            acc.x += a * v.x; acc.y += a * v.y; acc.z += a * v.z; acc.w += a * v.w;
        }
    }
    float* dst = ctx + (size_t)b * DV + dt * 1024 + t * 4;
    atomicAdd(dst + 0, acc.x);
    atomicAdd(dst + 1, acc.y);
    atomicAdd(dst + 2, acc.z);
    atomicAdd(dst + 3, acc.w);
}

extern "C" void kernel_launch(void* const* d_in, const int* in_sizes, int n_in,
                              void* d_out, int out_size, void* d_ws, size_t ws_size,
                              hipStream_t stream) {
    const float* query = (const float*)d_in[0];
    const float* pk    = (const float*)d_in[1];
    const float* value = (const float*)d_in[2];
    const float* Wq    = (const float*)d_in[3];
    const float* we    = (const float*)d_in[4];
    const int*   mask  = (const int*)d_in[5];

    float* out    = (float*)d_out;
    float* ctx    = out;                      // [B, 2H]
    float* alphas = out + BATCH * DV;         // [B, S]

    float* ws     = (float*)d_ws;
    float* qws    = ws;                                  // 16384 floats
    float* scores = ws + BATCH * HDIM;                   // 65536 floats
    float* partial = scores + BATCH * SEQ;               // B*NCH2*DV = 2M floats

    k1_q<<<HDIM / 4, 256, 0, stream>>>(query, Wq, qws);

    size_t need = (size_t)(BATCH * HDIM + BATCH * SEQ + BATCH * NCH2 * DV) * sizeof(float);
    if (ws_size >= need) {
        kf_fused<<<BATCH * NCH2, 256, 0, stream>>>(pk, qws, we, mask, value, scores, partial);
        kz_final<<<BATCH * 16, 256, 0, stream>>>(scores, partial, ctx, alphas);
    } else {
        k2_scores<<<(BATCH * SEQ) / 4, 256, 0, stream>>>(pk, qws, we, mask, scores);
        k3_softmax<<<BATCH, 256, 0, stream>>>(scores, alphas);
        (void)hipMemsetAsync(ctx, 0, (size_t)BATCH * DV * sizeof(float), stream);
        k4_atomic<<<BATCH * 64, 256, 0, stream>>>(value, alphas, ctx);
    }
}